// Round 9
// baseline (371.979 us; speedup 1.0000x reference)
//
#include <hip/hip_runtime.h>
#include <math.h>

#define B_  1024
#define T_  500
#define K_  100
#define NP_ 10000
#define CH  8           // steps per chunk
#define NCH 64          // 64*8 = 512 >= T_

__device__ __forceinline__ float lse2(float a, float b) {
    float m = fmaxf(a, b);
    return m + __logf(__expf(a - m) + __expf(b - m));
}

template<int CTRL, int RM>
__device__ __forceinline__ float dpp_add(float v) {
    int x = __builtin_amdgcn_update_dpp(0, __float_as_int(v), CTRL, RM, 0xf, true);
    return v + __int_as_float(x);
}

// Full-wave64 sum via DPP (pure VALU, no LDS). Result uniform via readlane(63).
__device__ __forceinline__ float wave_sum(float v) {
    v = dpp_add<0x111, 0xf>(v);   // row_shr:1
    v = dpp_add<0x112, 0xf>(v);   // row_shr:2
    v = dpp_add<0x114, 0xf>(v);   // row_shr:4
    v = dpp_add<0x118, 0xf>(v);   // row_shr:8
    v = dpp_add<0x142, 0xa>(v);   // row_bcast:15 -> rows 1,3
    v = dpp_add<0x143, 0xc>(v);   // row_bcast:31 -> rows 2,3
    return __int_as_float(__builtin_amdgcn_readlane(__float_as_int(v), 63));
}

// async global->LDS DMA: per-lane global src, linear LDS dest (base + lane*size)
#define GLOAD16(gp, lp) __builtin_amdgcn_global_load_lds( \
    (const __attribute__((address_space(1))) unsigned int*)(gp), \
    (__attribute__((address_space(3))) unsigned int*)(lp), 16, 0, 0)
#define GLOAD4(gp, lp) __builtin_amdgcn_global_load_lds( \
    (const __attribute__((address_space(1))) unsigned int*)(gp), \
    (__attribute__((address_space(3))) unsigned int*)(lp), 4, 0, 0)
#define WAITV0 asm volatile("s_waitcnt vmcnt(0)" ::: "memory")

// ---------------- precompute (unchanged, validated) ----------
__global__ __launch_bounds__(64, 4) void bkt_pre(
    const float* __restrict__ A, const float* __restrict__ trans,
    const float* __restrict__ obs, float* __restrict__ Qtab,
    float* __restrict__ Stab, float* __restrict__ LOtab)
{
    const int p = blockIdx.x;
    const int lane = threadIdx.x;
    const int k0 = lane, k1 = lane + 64;
    const bool has1 = (k1 < K_);
    const int k1c = has1 ? k1 : k0;
    const float m1 = has1 ? 1.f : 0.f;

    float4 t0 = *reinterpret_cast<const float4*>(trans + k0 * 4);
    float l00 = lse2(t0.x, t0.z), l01 = lse2(t0.y, t0.w);
    float lt000 = t0.x - l00, lt001 = t0.y - l01;
    float lt010 = t0.z - l00, lt011 = t0.w - l01;
    float4 t1 = *reinterpret_cast<const float4*>(trans + k1c * 4);
    float l10 = lse2(t1.x, t1.z), l11 = lse2(t1.y, t1.w);
    float lt100 = t1.x - l10, lt101 = t1.y - l11;
    float lt110 = t1.z - l10, lt111 = t1.w - l11;

    const float* ar = A + (size_t)p * K_;
    float c0 = ar[k0];
    float c1 = ar[k1c] * m1;

    float sc  = wave_sum(c0 + c1);
    float q00 = wave_sum(c0 * lt000 + c1 * lt100);
    float q01 = wave_sum(c0 * lt001 + c1 * lt101);
    float q10 = wave_sum(c0 * lt010 + c1 * lt110);
    float q11 = wave_sum(c0 * lt011 + c1 * lt111);

    float4 ob = *reinterpret_cast<const float4*>(obs + (size_t)p * 4);
    float l0 = lse2(ob.x, ob.y), l1 = lse2(ob.z, ob.w);

    if (lane == 0) {
        reinterpret_cast<float4*>(Qtab)[p] = make_float4(q00, q01, q10, q11);
        Stab[p] = sc;
        reinterpret_cast<float4*>(LOtab)[p] =
            make_float4(ob.x - l0, ob.y - l0, ob.z - l1, ob.w - l1);
    }
}

// ---------------- main scan: P/R chunk factorization (CH=8) ----------------
// Within a chunk (alpha0 = chunk-start alpha):
//   a2_u = R_u + sum_{j<u} P[u][j] * a3_j          (exact identity)
//   P[u][j] = sum_k c_u c_j prod_{j<i<u}(1-c_i)    (alpha-independent)
//   R_u    = sum_k c_u alpha0 prod_{i<u}(1-c_i)
// P and R are computed in a fully parallel pre-pass; the serial pass per step
// is only add -> lse2 -> scatter-fma (critical path ~60cy).
__global__ __launch_bounds__(64, 1) void bkt_main(
    const int* __restrict__ corr, const int* __restrict__ kc,
    const int* __restrict__ problem, const float* __restrict__ A,
    const float* __restrict__ init, const float* __restrict__ Qtab,
    const float* __restrict__ Stab, const float* __restrict__ LOtab,
    float* __restrict__ out)
{
    const int b = blockIdx.x;
    const int lane = threadIdx.x;
    const int k1 = lane + 64;
    const bool has1 = (k1 < K_);
    const int k1c = has1 ? k1 : lane;
    const float m1 = has1 ? 1.f : 0.f;

    // LDS staging (~7.3 KB)
    __shared__ float  s_c[2][CH * K_];      // A-rows per step     6400 B
    __shared__ float4 s_ql[2][2 * CH];      // Q[0..7] L[8..15]     512 B
    __shared__ float  s_s[2][CH];           //                       64 B
    __shared__ int    s_idx[3][3 * CH];     // kc|pr|y               288 B

    const int* kcb = kc + (size_t)b * T_;
    const int* prb = problem + (size_t)b * T_;
    const int* cob = corr + (size_t)b * T_;
    float* outp = out + (size_t)b * T_ * 2;

    // alpha init: log_softmax(init_logits, axis=1)
    float al00, al01, al10 = 0.f, al11 = 0.f;
    {
        float2 x = *reinterpret_cast<const float2*>(init + lane * 2);
        float l = lse2(x.x, x.y);
        al00 = x.x - l; al01 = x.y - l;
    }
    {
        float2 x = *reinterpret_cast<const float2*>(init + k1c * 2);
        float l = lse2(x.x, x.y);
        al10 = (x.x - l) * m1; al11 = (x.y - l) * m1;
    }

    // idx stage: lanes 0..7 kc, 8..15 pr, 16..23 y (clamped t)
#define STAGEIDX(cn, ib) {                                                \
        int tt_ = (cn) * CH + (lane & 7);                                 \
        tt_ = tt_ < T_ ? tt_ : T_ - 1;                                    \
        const int* src_ = (lane < 8) ? (kcb + tt_)                        \
                        : (lane < 16) ? (prb + tt_) : (cob + tt_);        \
        if (lane < 24) GLOAD4(src_, &s_idx[ib][0]);                       \
    }

#define GATHER(ib, db) {                                                  \
        int id_ = s_idx[ib][lane & 15];                                   \
        const float* qls_ = (lane < 8) ? (Qtab + (size_t)id_ * 4)         \
                                       : (LOtab + (size_t)id_ * 4);       \
        if (lane < 16) GLOAD16(qls_, &s_ql[db][0]);                       \
        if (lane < 8)  GLOAD4(Stab + id_, &s_s[db][0]);                   \
        _Pragma("unroll")                                                 \
        for (int j_ = 0; j_ < 4; ++j_) {                                  \
            int f_ = j_ * 64 + lane;                                      \
            unsigned tf_ = ((unsigned)f_ * 5243u) >> 17;    /* f/25 */    \
            int q_ = f_ - (int)tf_ * 25;                                  \
            int kcv_ = s_idx[ib][tf_];                                    \
            if (f_ < CH * 25)                                             \
                GLOAD16(A + (size_t)kcv_ * K_ + q_ * 4, &s_c[db][j_ * 256]); \
        }                                                                 \
    }

    // ---- prologue ----
    STAGEIDX(0, 0);
    STAGEIDX(1, 1);
    WAITV0;
    GATHER(0, 0);

#pragma unroll 1
    for (int n = 0; n < NCH; ++n) {
        WAITV0;                               // chunk-n data + idx n+1 landed
        STAGEIDX(n + 2, (n + 2) % 3);
        GATHER((n + 1) % 3, (n + 1) & 1);

        const float*  cbuf = s_c[n & 1];
        const float4* qlb  = s_ql[n & 1];
        const float*  sb   = s_s[n & 1];
        const int*    ibp  = s_idx[n % 3];

        // ---- load c rows into registers; d = 1-c ----
        float c0r[CH], c1r[CH], d0r[CH], d1r[CH];
#pragma unroll
        for (int u = 0; u < CH; ++u) {
            c0r[u] = cbuf[u * K_ + lane];
            c1r[u] = cbuf[u * K_ + k1c] * m1;
        }
#pragma unroll
        for (int u = 0; u < CH; ++u) {
            d0r[u] = 1.f - c0r[u];
            d1r[u] = 1.f - c1r[u];
        }

        // ---- g precompute (uniform per step) ----
        float g0[CH], g1[CH], g2[CH], g3[CH];
#pragma unroll
        for (int u = 0; u < CH; ++u) {
            float4 Q = qlb[u];
            float4 L = qlb[CH + u];
            float  S = sb[u];
            int    y = ibp[16 + u];
            float hs0 = ((y == 0) ? L.x : L.y) * S;
            float hs1 = ((y == 0) ? L.z : L.w) * S;
            g0[u] = hs0 + Q.x; g1[u] = hs1 + Q.y;
            g2[u] = hs0 + Q.z; g3[u] = hs1 + Q.w;
        }

        // ---- P matrix (lower triangular), fully parallel ----
        float P[CH][CH];
#pragma unroll
        for (int j = 0; j < CH - 1; ++j) {
            float v0 = c0r[j], v1 = c1r[j];
#pragma unroll
            for (int t = j + 1; t < CH; ++t) {
                P[t][j] = wave_sum(c0r[t] * v0 + c1r[t] * v1);
                v0 *= d0r[t]; v1 *= d1r[t];
            }
        }

        // ---- a2acc init = R (chunk-start alpha weighted) ----
        float a2acc0[CH], a2acc1[CH];
        {
            float w00 = al00, w01 = al01, w10 = al10, w11 = al11;
#pragma unroll
            for (int u = 0; u < CH; ++u) {
                a2acc0[u] = wave_sum(c0r[u] * w00 + c1r[u] * w10);
                a2acc1[u] = wave_sum(c0r[u] * w01 + c1r[u] * w11);
                w00 *= d0r[u]; w01 *= d0r[u];
                w10 *= d1r[u]; w11 *= d1r[u];
            }
        }

        // ---- serial pass: tiny critical path ----
        float keep0 = 0.f, keep1 = 0.f;
#pragma unroll
        for (int u = 0; u < CH; ++u) {
            float a20 = a2acc0[u], a21 = a2acc1[u];
            keep0 = (lane == u) ? a20 : keep0;
            keep1 = (lane == u) ? a21 : keep1;
            float a30 = lse2(g0[u] + a20, g1[u] + a21);
            float a31 = lse2(g2[u] + a20, g3[u] + a21);
            // scatter into future steps (v=u+1 first: shortest path to next step)
#pragma unroll
            for (int v = u + 1; v < CH; ++v) {
                a2acc0[v] += P[v][u] * a30;
                a2acc1[v] += P[v][u] * a31;
            }
            // alpha update (off critical path; feeds next chunk's R)
            al00 += c0r[u] * (a30 - al00);
            al01 += c0r[u] * (a31 - al01);
            al10 += c1r[u] * (a30 - al10);
            al11 += c1r[u] * (a31 - al11);
        }

        // ---- py epilogue: lanes 0..7, one step each ----
        if (lane < CH) {
            float4 L = qlb[CH + lane];
            float  S = sb[lane];
            float h00 = L.x * S, h01 = L.y * S, h10 = L.z * S, h11 = L.w * S;
            float py0 = lse2(h00 + keep0, h10 + keep1);
            float py1 = lse2(h01 + keep0, h11 + keep1);
            float nrm = lse2(py0, py1);
            int t = n * CH + lane;
            if (t < T_)
                *reinterpret_cast<float2*>(outp + (size_t)t * 2) =
                    make_float2(py0 - nrm, py1 - nrm);
        }
    }
#undef STAGEIDX
#undef GATHER
}

extern "C" void kernel_launch(void* const* d_in, const int* in_sizes, int n_in,
                              void* d_out, int out_size, void* d_ws, size_t ws_size,
                              hipStream_t stream) {
    const int*   corr    = (const int*)d_in[0];
    const int*   kc      = (const int*)d_in[1];
    const int*   problem = (const int*)d_in[2];
    const float* A       = (const float*)d_in[3];
    const float* trans   = (const float*)d_in[4];
    const float* obs     = (const float*)d_in[5];
    const float* init    = (const float*)d_in[6];
    float* out = (float*)d_out;

    // workspace layout: Qtab (NP*4 f32) | LOtab (NP*4 f32) | Stab (NP f32)
    float* Qtab  = (float*)d_ws;
    float* LOtab = Qtab + (size_t)NP_ * 4;
    float* Stab  = LOtab + (size_t)NP_ * 4;

    bkt_pre<<<NP_, 64, 0, stream>>>(A, trans, obs, Qtab, Stab, LOtab);
    bkt_main<<<B_, 64, 0, stream>>>(corr, kc, problem, A, init, Qtab, Stab, LOtab, out);
}

// Round 10
// 361.575 us; speedup vs baseline: 1.0288x; 1.0288x over previous
//
#include <hip/hip_runtime.h>
#include <math.h>

#define B_  1024
#define T_  500
#define K_  100
#define NP_ 10000
#define CH  16          // steps per chunk (per chain)
#define NCH 32          // 32*16 = 512 >= T_

__device__ __forceinline__ float lse2(float a, float b) {
    float m = fmaxf(a, b);
    return m + __logf(__expf(a - m) + __expf(b - m));
}

template<int CTRL, int RM>
__device__ __forceinline__ float dpp_add(float v) {
    int x = __builtin_amdgcn_update_dpp(0, __float_as_int(v), CTRL, RM, 0xf, true);
    return v + __int_as_float(x);
}

// Full-wave64 sum via DPP (pure VALU, no LDS). Result uniform via readlane(63).
__device__ __forceinline__ float wave_sum(float v) {
    v = dpp_add<0x111, 0xf>(v);   // row_shr:1
    v = dpp_add<0x112, 0xf>(v);   // row_shr:2
    v = dpp_add<0x114, 0xf>(v);   // row_shr:4
    v = dpp_add<0x118, 0xf>(v);   // row_shr:8
    v = dpp_add<0x142, 0xa>(v);   // row_bcast:15 -> rows 1,3
    v = dpp_add<0x143, 0xc>(v);   // row_bcast:31 -> rows 2,3
    return __int_as_float(__builtin_amdgcn_readlane(__float_as_int(v), 63));
}

// async global->LDS DMA: per-lane global src, linear LDS dest (base + lane*size)
#define GLOAD16(gp, lp) __builtin_amdgcn_global_load_lds( \
    (const __attribute__((address_space(1))) unsigned int*)(gp), \
    (__attribute__((address_space(3))) unsigned int*)(lp), 16, 0, 0)
#define GLOAD4(gp, lp) __builtin_amdgcn_global_load_lds( \
    (const __attribute__((address_space(1))) unsigned int*)(gp), \
    (__attribute__((address_space(3))) unsigned int*)(lp), 4, 0, 0)
#define WAITV0 asm volatile("s_waitcnt vmcnt(0)" ::: "memory")

// ---------------- precompute (unchanged, validated) ----------
__global__ __launch_bounds__(64, 4) void bkt_pre(
    const float* __restrict__ A, const float* __restrict__ trans,
    const float* __restrict__ obs, float* __restrict__ Qtab,
    float* __restrict__ Stab, float* __restrict__ LOtab)
{
    const int p = blockIdx.x;
    const int lane = threadIdx.x;
    const int k0 = lane, k1 = lane + 64;
    const bool has1 = (k1 < K_);
    const int k1c = has1 ? k1 : k0;
    const float m1 = has1 ? 1.f : 0.f;

    float4 t0 = *reinterpret_cast<const float4*>(trans + k0 * 4);
    float l00 = lse2(t0.x, t0.z), l01 = lse2(t0.y, t0.w);
    float lt000 = t0.x - l00, lt001 = t0.y - l01;
    float lt010 = t0.z - l00, lt011 = t0.w - l01;
    float4 t1 = *reinterpret_cast<const float4*>(trans + k1c * 4);
    float l10 = lse2(t1.x, t1.z), l11 = lse2(t1.y, t1.w);
    float lt100 = t1.x - l10, lt101 = t1.y - l11;
    float lt110 = t1.z - l10, lt111 = t1.w - l11;

    const float* ar = A + (size_t)p * K_;
    float c0 = ar[k0];
    float c1 = ar[k1c] * m1;

    float sc  = wave_sum(c0 + c1);
    float q00 = wave_sum(c0 * lt000 + c1 * lt100);
    float q01 = wave_sum(c0 * lt001 + c1 * lt101);
    float q10 = wave_sum(c0 * lt010 + c1 * lt110);
    float q11 = wave_sum(c0 * lt011 + c1 * lt111);

    float4 ob = *reinterpret_cast<const float4*>(obs + (size_t)p * 4);
    float l0 = lse2(ob.x, ob.y), l1 = lse2(ob.z, ob.w);

    if (lane == 0) {
        reinterpret_cast<float4*>(Qtab)[p] = make_float4(q00, q01, q10, q11);
        Stab[p] = sc;
        reinterpret_cast<float4*>(LOtab)[p] =
            make_float4(ob.x - l0, ob.y - l0, ob.z - l1, ob.w - l1);
    }
}

// ---------------- main scan: 2 chains per wave, round-7 recurrence ----------
__global__ __launch_bounds__(64, 1) void bkt_main(
    const int* __restrict__ corr, const int* __restrict__ kc,
    const int* __restrict__ problem, const float* __restrict__ A,
    const float* __restrict__ init, const float* __restrict__ Qtab,
    const float* __restrict__ Stab, const float* __restrict__ LOtab,
    float* __restrict__ out)
{
    const int b0 = 2 * blockIdx.x;
    const int b1 = b0 + 1;
    const int lane = threadIdx.x;
    const int k1 = lane + 64;
    const bool has1 = (k1 < K_);
    const int k1c = has1 ? k1 : lane;
    const float m1 = has1 ? 1.f : 0.f;

    // LDS staging (~29 KB)
    __shared__ float  s_c[2][2][CH * K_];    // A-rows: [dbuf][chain]  25600 B
    __shared__ float4 s_ql[2][2][2 * CH];    // Q[0..15] L[16..31]      2048 B
    __shared__ float  s_s[2][2][CH];         //                          256 B
    __shared__ int    s_idx[3][2][3 * CH];   // kc|pr|y                 1152 B

    const int* kcbA = kc + (size_t)b0 * T_;
    const int* prbA = problem + (size_t)b0 * T_;
    const int* cobA = corr + (size_t)b0 * T_;
    const int* kcbB = kc + (size_t)b1 * T_;
    const int* prbB = problem + (size_t)b1 * T_;
    const int* cobB = corr + (size_t)b1 * T_;
    float* outA = out + (size_t)b0 * T_ * 2;
    float* outB = out + (size_t)b1 * T_ * 2;

    // alpha init (same tables for both chains; they diverge after step 0)
    float iA0, iA1, iB0, iB1;
    {
        float2 x = *reinterpret_cast<const float2*>(init + lane * 2);
        float l = lse2(x.x, x.y);
        iA0 = x.x - l; iA1 = x.y - l;
    }
    {
        float2 x = *reinterpret_cast<const float2*>(init + k1c * 2);
        float l = lse2(x.x, x.y);
        iB0 = (x.x - l) * m1; iB1 = (x.y - l) * m1;
    }
    float alA00 = iA0, alA01 = iA1, alA10 = iB0, alA11 = iB1;
    float alB00 = iA0, alB01 = iA1, alB10 = iB0, alB11 = iB1;

    // idx stage: per chain lanes 0-15 kc, 16-31 pr, 32-47 y
#define STAGEIDX(cn, ib) {                                                \
        int tt_ = (cn) * CH + (lane & 15);                                \
        tt_ = tt_ < T_ ? tt_ : T_ - 1;                                    \
        const int* sA_ = (lane < 16) ? (kcbA + tt_)                       \
                       : (lane < 32) ? (prbA + tt_) : (cobA + tt_);       \
        if (lane < 48) GLOAD4(sA_, &s_idx[ib][0][0]);                     \
        const int* sB_ = (lane < 16) ? (kcbB + tt_)                       \
                       : (lane < 32) ? (prbB + tt_) : (cobB + tt_);       \
        if (lane < 48) GLOAD4(sB_, &s_idx[ib][1][0]);                     \
    }

#define GATHER(ib, db) {                                                  \
        int idA_ = s_idx[ib][0][lane & 31];                               \
        const float* qA_ = (lane < 16) ? (Qtab + (size_t)idA_ * 4)        \
                                       : (LOtab + (size_t)idA_ * 4);      \
        if (lane < 32) GLOAD16(qA_, &s_ql[db][0][0]);                     \
        if (lane < 16) GLOAD4(Stab + idA_, &s_s[db][0][0]);               \
        int idB_ = s_idx[ib][1][lane & 31];                               \
        const float* qB_ = (lane < 16) ? (Qtab + (size_t)idB_ * 4)        \
                                       : (LOtab + (size_t)idB_ * 4);      \
        if (lane < 32) GLOAD16(qB_, &s_ql[db][1][0]);                     \
        if (lane < 16) GLOAD4(Stab + idB_, &s_s[db][1][0]);               \
        _Pragma("unroll")                                                 \
        for (int j_ = 0; j_ < 7; ++j_) {                                  \
            int f_ = j_ * 64 + lane;                                      \
            unsigned tf_ = ((unsigned)f_ * 5243u) >> 17;    /* f/25 */    \
            int q_ = f_ - (int)tf_ * 25;                                  \
            int kvA_ = s_idx[ib][0][tf_];                                 \
            if (f_ < CH * 25)                                             \
                GLOAD16(A + (size_t)kvA_ * K_ + q_ * 4, &s_c[db][0][j_ * 256]); \
            int kvB_ = s_idx[ib][1][tf_];                                 \
            if (f_ < CH * 25)                                             \
                GLOAD16(A + (size_t)kvB_ * K_ + q_ * 4, &s_c[db][1][j_ * 256]); \
        }                                                                 \
    }

    // ---- prologue ----
    STAGEIDX(0, 0);
    STAGEIDX(1, 1);
    WAITV0;
    GATHER(0, 0);

#pragma unroll 1
    for (int n = 0; n < NCH; ++n) {
        WAITV0;                               // chunk-n data + idx n+1 landed
        STAGEIDX(n + 2, (n + 2) % 3);
        GATHER((n + 1) % 3, (n + 1) & 1);

        const float*  cbA = s_c[n & 1][0];
        const float*  cbB = s_c[n & 1][1];
        const float4* qlA = s_ql[n & 1][0];
        const float4* qlB = s_ql[n & 1][1];
        const float*  sbA = s_s[n & 1][0];
        const float*  sbB = s_s[n & 1][1];
        const int*    ipA = s_idx[n % 3][0];
        const int*    ipB = s_idx[n % 3][1];

        // ---- prime a2 for step 0 of both chains ----
        float caA0 = cbA[lane],        caA1 = cbA[k1c] * m1;
        float caB0 = cbB[lane],        caB1 = cbB[k1c] * m1;
        float a2A0 = wave_sum(caA0 * alA00 + caA1 * alA10);
        float a2B0 = wave_sum(caB0 * alB00 + caB1 * alB10);
        float a2A1 = wave_sum(caA0 * alA01 + caA1 * alA11);
        float a2B1 = wave_sum(caB0 * alB01 + caB1 * alB11);

        float keepA0 = 0.f, keepA1 = 0.f, keepB0 = 0.f, keepB1 = 0.f;

        // prefetch step-0 operands + c of step 1
        float4 QA = qlA[0], LA = qlA[CH];
        float4 QB = qlB[0], LB = qlB[CH];
        float  SA = sbA[0], SB = sbB[0];
        int    yA = ipA[32], yB = ipB[32];
        float cbA0 = cbA[K_ + lane], cbA1 = cbA[K_ + k1c] * m1;
        float cbB0 = cbB[K_ + lane], cbB1 = cbB[K_ + k1c] * m1;

#pragma unroll
        for (int u = 0; u < CH - 1; ++u) {
            keepA0 = (lane == u) ? a2A0 : keepA0;
            keepA1 = (lane == u) ? a2A1 : keepA1;
            keepB0 = (lane == u) ? a2B0 : keepB0;
            keepB1 = (lane == u) ? a2B1 : keepB1;
            float hsA0 = ((yA == 0) ? LA.x : LA.y) * SA;
            float hsA1 = ((yA == 0) ? LA.z : LA.w) * SA;
            float hsB0 = ((yB == 0) ? LB.x : LB.y) * SB;
            float hsB1 = ((yB == 0) ? LB.z : LB.w) * SB;
            // W/U prep (independent of a3) — both chains interleaved
            float xA0 = cbA0 * caA0, xA1 = cbA1 * caA1;
            float xB0 = cbB0 * caB0, xB1 = cbB1 * caB1;
            float tuA0 = cbA0 - xA0, tuA1 = cbA1 - xA1;
            float tuB0 = cbB0 - xB0, tuB1 = cbB1 - xB1;
            float UA0 = wave_sum(tuA0 * alA00 + tuA1 * alA10);
            float UB0 = wave_sum(tuB0 * alB00 + tuB1 * alB10);
            float UA1 = wave_sum(tuA0 * alA01 + tuA1 * alA11);
            float UB1 = wave_sum(tuB0 * alB01 + tuB1 * alB11);
            float WA = wave_sum(xA0 + xA1);
            float WB = wave_sum(xB0 + xB1);
            // critical scalar chains (independent)
            float a3A0 = lse2(hsA0 + QA.x + a2A0, hsA1 + QA.y + a2A1);
            float a3B0 = lse2(hsB0 + QB.x + a2B0, hsB1 + QB.y + a2B1);
            float a3A1 = lse2(hsA0 + QA.z + a2A0, hsA1 + QA.w + a2A1);
            float a3B1 = lse2(hsB0 + QB.z + a2B0, hsB1 + QB.w + a2B1);
            // alpha updates (pre-update alpha already consumed by U)
            alA00 += caA0 * (a3A0 - alA00);
            alA01 += caA0 * (a3A1 - alA01);
            alA10 += caA1 * (a3A0 - alA10);
            alA11 += caA1 * (a3A1 - alA11);
            alB00 += caB0 * (a3B0 - alB00);
            alB01 += caB0 * (a3B1 - alB01);
            alB10 += caB1 * (a3B0 - alB10);
            alB11 += caB1 * (a3B1 - alB11);
            // next a2 = U + W*a3
            a2A0 = UA0 + WA * a3A0;
            a2A1 = UA1 + WA * a3A1;
            a2B0 = UB0 + WB * a3B0;
            a2B1 = UB1 + WB * a3B1;
            caA0 = cbA0; caA1 = cbA1;
            caB0 = cbB0; caB1 = cbB1;
            // prefetch step u+1 operands
            QA = qlA[u + 1]; LA = qlA[CH + u + 1];
            QB = qlB[u + 1]; LB = qlB[CH + u + 1];
            SA = sbA[u + 1]; SB = sbB[u + 1];
            yA = ipA[32 + u + 1]; yB = ipB[32 + u + 1];
            if (u + 2 < CH) {
                cbA0 = cbA[(u + 2) * K_ + lane];
                cbA1 = cbA[(u + 2) * K_ + k1c] * m1;
                cbB0 = cbB[(u + 2) * K_ + lane];
                cbB1 = cbB[(u + 2) * K_ + k1c] * m1;
            }
        }
        // ---- last step of chunk ----
        {
            keepA0 = (lane == (CH - 1)) ? a2A0 : keepA0;
            keepA1 = (lane == (CH - 1)) ? a2A1 : keepA1;
            keepB0 = (lane == (CH - 1)) ? a2B0 : keepB0;
            keepB1 = (lane == (CH - 1)) ? a2B1 : keepB1;
            float hsA0 = ((yA == 0) ? LA.x : LA.y) * SA;
            float hsA1 = ((yA == 0) ? LA.z : LA.w) * SA;
            float hsB0 = ((yB == 0) ? LB.x : LB.y) * SB;
            float hsB1 = ((yB == 0) ? LB.z : LB.w) * SB;
            float a3A0 = lse2(hsA0 + QA.x + a2A0, hsA1 + QA.y + a2A1);
            float a3B0 = lse2(hsB0 + QB.x + a2B0, hsB1 + QB.y + a2B1);
            float a3A1 = lse2(hsA0 + QA.z + a2A0, hsA1 + QA.w + a2A1);
            float a3B1 = lse2(hsB0 + QB.z + a2B0, hsB1 + QB.w + a2B1);
            alA00 += caA0 * (a3A0 - alA00);
            alA01 += caA0 * (a3A1 - alA01);
            alA10 += caA1 * (a3A0 - alA10);
            alA11 += caA1 * (a3A1 - alA11);
            alB00 += caB0 * (a3B0 - alB00);
            alB01 += caB0 * (a3B1 - alB01);
            alB10 += caB1 * (a3B0 - alB10);
            alB11 += caB1 * (a3B1 - alB11);
        }
        // ---- epilogue: batched py, lanes 0..15 (one step each), both chains --
        if (lane < CH) {
            int t = n * CH + lane;
            {
                float4 L = qlA[CH + lane];
                float  S = sbA[lane];
                float h00 = L.x * S, h01 = L.y * S, h10 = L.z * S, h11 = L.w * S;
                float py0 = lse2(h00 + keepA0, h10 + keepA1);
                float py1 = lse2(h01 + keepA0, h11 + keepA1);
                float nrm = lse2(py0, py1);
                if (t < T_)
                    *reinterpret_cast<float2*>(outA + (size_t)t * 2) =
                        make_float2(py0 - nrm, py1 - nrm);
            }
            {
                float4 L = qlB[CH + lane];
                float  S = sbB[lane];
                float h00 = L.x * S, h01 = L.y * S, h10 = L.z * S, h11 = L.w * S;
                float py0 = lse2(h00 + keepB0, h10 + keepB1);
                float py1 = lse2(h01 + keepB0, h11 + keepB1);
                float nrm = lse2(py0, py1);
                if (t < T_)
                    *reinterpret_cast<float2*>(outB + (size_t)t * 2) =
                        make_float2(py0 - nrm, py1 - nrm);
            }
        }
    }
#undef STAGEIDX
#undef GATHER
}

extern "C" void kernel_launch(void* const* d_in, const int* in_sizes, int n_in,
                              void* d_out, int out_size, void* d_ws, size_t ws_size,
                              hipStream_t stream) {
    const int*   corr    = (const int*)d_in[0];
    const int*   kc      = (const int*)d_in[1];
    const int*   problem = (const int*)d_in[2];
    const float* A       = (const float*)d_in[3];
    const float* trans   = (const float*)d_in[4];
    const float* obs     = (const float*)d_in[5];
    const float* init    = (const float*)d_in[6];
    float* out = (float*)d_out;

    // workspace layout: Qtab (NP*4 f32) | LOtab (NP*4 f32) | Stab (NP f32)
    float* Qtab  = (float*)d_ws;
    float* LOtab = Qtab + (size_t)NP_ * 4;
    float* Stab  = LOtab + (size_t)NP_ * 4;

    bkt_pre<<<NP_, 64, 0, stream>>>(A, trans, obs, Qtab, Stab, LOtab);
    bkt_main<<<B_ / 2, 64, 0, stream>>>(corr, kc, problem, A, init,
                                        Qtab, Stab, LOtab, out);
}

// Round 11
// 262.936 us; speedup vs baseline: 1.4147x; 1.3751x over previous
//
#include <hip/hip_runtime.h>
#include <math.h>

#define B_  1024
#define T_  500
#define K_  100
#define NP_ 10000
#define CH  16          // steps per chunk
#define NCH 32          // 32*16 = 512 >= T_

#define LOG2E_ 1.4426950408889634f
#define LN2_   0.6931471805599453f

// natural-log lse2 (used in precompute only)
__device__ __forceinline__ float lse2(float a, float b) {
    float m = fmaxf(a, b);
    return m + __logf(__expf(a - m) + __expf(b - m));
}

// base-2 lse2: max + log2(1 + 2^(min-max)); 2 trans ops, no conversion muls
__device__ __forceinline__ float lseb(float a, float b) {
    float mx = fmaxf(a, b);
    float d  = fminf(a, b) - mx;          // <= 0
    return mx + log2f(1.f + exp2f(d));
}

template<int CTRL, int RM>
__device__ __forceinline__ float dpp_add(float v) {
    int x = __builtin_amdgcn_update_dpp(0, __float_as_int(v), CTRL, RM, 0xf, true);
    return v + __int_as_float(x);
}

// Full-wave64 sum via DPP (pure VALU, no LDS). Result uniform via readlane(63).
__device__ __forceinline__ float wave_sum(float v) {
    v = dpp_add<0x111, 0xf>(v);   // row_shr:1
    v = dpp_add<0x112, 0xf>(v);   // row_shr:2
    v = dpp_add<0x114, 0xf>(v);   // row_shr:4
    v = dpp_add<0x118, 0xf>(v);   // row_shr:8
    v = dpp_add<0x142, 0xa>(v);   // row_bcast:15 -> rows 1,3
    v = dpp_add<0x143, 0xc>(v);   // row_bcast:31 -> rows 2,3
    return __int_as_float(__builtin_amdgcn_readlane(__float_as_int(v), 63));
}

// async global->LDS DMA: per-lane global src, linear LDS dest (base + lane*size)
#define GLOAD16(gp, lp) __builtin_amdgcn_global_load_lds( \
    (const __attribute__((address_space(1))) unsigned int*)(gp), \
    (__attribute__((address_space(3))) unsigned int*)(lp), 16, 0, 0)
#define GLOAD4(gp, lp) __builtin_amdgcn_global_load_lds( \
    (const __attribute__((address_space(1))) unsigned int*)(gp), \
    (__attribute__((address_space(3))) unsigned int*)(lp), 4, 0, 0)
#define WAITV0 asm volatile("s_waitcnt vmcnt(0)" ::: "memory")

// ---------------- precompute ----------
// Qtab[p] = (sum_k A[p,k] * log_softmax(trans,axis=1)[k]) * LOG2E
// LOtab[p] = log_softmax(obs[p], over o) * LOG2E
// NOTE: sum_k A[p,k] == 1 exactly (A is softmax over k), so no Stab.
__global__ __launch_bounds__(64, 4) void bkt_pre(
    const float* __restrict__ A, const float* __restrict__ trans,
    const float* __restrict__ obs, float* __restrict__ Qtab,
    float* __restrict__ LOtab)
{
    const int p = blockIdx.x;
    const int lane = threadIdx.x;
    const int k0 = lane, k1 = lane + 64;
    const bool has1 = (k1 < K_);
    const int k1c = has1 ? k1 : k0;
    const float m1 = has1 ? 1.f : 0.f;

    float4 t0 = *reinterpret_cast<const float4*>(trans + k0 * 4);
    float l00 = lse2(t0.x, t0.z), l01 = lse2(t0.y, t0.w);
    float lt000 = t0.x - l00, lt001 = t0.y - l01;
    float lt010 = t0.z - l00, lt011 = t0.w - l01;
    float4 t1 = *reinterpret_cast<const float4*>(trans + k1c * 4);
    float l10 = lse2(t1.x, t1.z), l11 = lse2(t1.y, t1.w);
    float lt100 = t1.x - l10, lt101 = t1.y - l11;
    float lt110 = t1.z - l10, lt111 = t1.w - l11;

    const float* ar = A + (size_t)p * K_;
    float c0 = ar[k0];
    float c1 = ar[k1c] * m1;

    float q00 = wave_sum(c0 * lt000 + c1 * lt100);
    float q01 = wave_sum(c0 * lt001 + c1 * lt101);
    float q10 = wave_sum(c0 * lt010 + c1 * lt110);
    float q11 = wave_sum(c0 * lt011 + c1 * lt111);

    float4 ob = *reinterpret_cast<const float4*>(obs + (size_t)p * 4);
    float l0 = lse2(ob.x, ob.y), l1 = lse2(ob.z, ob.w);

    if (lane == 0) {
        reinterpret_cast<float4*>(Qtab)[p] =
            make_float4(q00 * LOG2E_, q01 * LOG2E_, q10 * LOG2E_, q11 * LOG2E_);
        reinterpret_cast<float4*>(LOtab)[p] =
            make_float4((ob.x - l0) * LOG2E_, (ob.y - l0) * LOG2E_,
                        (ob.z - l1) * LOG2E_, (ob.w - l1) * LOG2E_);
    }
}

// ---------------- main scan: log2-domain, batched W/g, U/W recurrence -------
__global__ __launch_bounds__(64, 1) void bkt_main(
    const int* __restrict__ corr, const int* __restrict__ kc,
    const int* __restrict__ problem, const float* __restrict__ A,
    const float* __restrict__ init, const float* __restrict__ Qtab,
    const float* __restrict__ LOtab, float* __restrict__ out)
{
    const int b = blockIdx.x;
    const int lane = threadIdx.x;
    const int k1 = lane + 64;
    const bool has1 = (k1 < K_);
    const int k1c = has1 ? k1 : lane;
    const float m1 = has1 ? 1.f : 0.f;

    // LDS staging (~14.6 KB)
    __shared__ float  s_c[2][CH * K_];      // A-rows per step    12800 B
    __shared__ float4 s_ql[2][2 * CH];      // Q[0..15] L[16..31]  1024 B
    __shared__ int    s_idx[3][3 * CH];     // kc|pr|y              576 B
    __shared__ float4 s_g[2][CH];           // per-step g           512 B

    const int* kcb = kc + (size_t)b * T_;
    const int* prb = problem + (size_t)b * T_;
    const int* cob = corr + (size_t)b * T_;
    float* outp = out + (size_t)b * T_ * 2;

    // alpha init: log_softmax(init_logits, axis=1) * LOG2E
    float al00, al01, al10 = 0.f, al11 = 0.f;
    {
        float2 x = *reinterpret_cast<const float2*>(init + lane * 2);
        float l = lse2(x.x, x.y);
        al00 = (x.x - l) * LOG2E_; al01 = (x.y - l) * LOG2E_;
    }
    {
        float2 x = *reinterpret_cast<const float2*>(init + k1c * 2);
        float l = lse2(x.x, x.y);
        al10 = (x.x - l) * LOG2E_ * m1; al11 = (x.y - l) * LOG2E_ * m1;
    }

    // idx stage: lanes 0..15 kc, 16..31 pr, 32..47 y (clamped t)
#define STAGEIDX(cn, ib) {                                                \
        int tt_ = (cn) * CH + (lane & 15);                                \
        tt_ = tt_ < T_ ? tt_ : T_ - 1;                                    \
        const int* src_ = (lane < 16) ? (kcb + tt_)                       \
                        : (lane < 32) ? (prb + tt_) : (cob + tt_);        \
        if (lane < 48) GLOAD4(src_, &s_idx[ib][0]);                       \
    }

#define GATHER(ib, db) {                                                  \
        int id_ = s_idx[ib][lane & 31];                                   \
        const float* qls_ = (lane < 16) ? (Qtab + (size_t)id_ * 4)        \
                                        : (LOtab + (size_t)id_ * 4);      \
        if (lane < 32) GLOAD16(qls_, &s_ql[db][0]);                       \
        _Pragma("unroll")                                                 \
        for (int j_ = 0; j_ < 7; ++j_) {                                  \
            int f_ = j_ * 64 + lane;                                      \
            unsigned tf_ = ((unsigned)f_ * 5243u) >> 17;    /* f/25 */    \
            int q_ = f_ - (int)tf_ * 25;                                  \
            int kcv_ = s_idx[ib][tf_];                                    \
            if (f_ < CH * 25)                                             \
                GLOAD16(A + (size_t)kcv_ * K_ + q_ * 4, &s_c[db][j_ * 256]); \
        }                                                                 \
    }

    // ---- prologue ----
    STAGEIDX(0, 0);
    STAGEIDX(1, 1);
    WAITV0;
    GATHER(0, 0);

#pragma unroll 1
    for (int n = 0; n < NCH; ++n) {
        WAITV0;                               // chunk-n data + idx n+1 landed
        STAGEIDX(n + 2, (n + 2) % 3);
        GATHER((n + 1) % 3, (n + 1) & 1);

        const float*  cbuf = s_c[n & 1];
        const float4* qlb  = s_ql[n & 1];
        const int*    ibp  = s_idx[n % 3];
        const int db = n & 1;

        // ---- c rows into registers (statically indexed) ----
        float c0r[CH], c1r[CH];
#pragma unroll
        for (int u = 0; u < CH; ++u) {
            c0r[u] = cbuf[u * K_ + lane];
            c1r[u] = cbuf[u * K_ + k1c] * m1;
        }

        // ---- g pre-pass: lanes 0..15, step = lane (S==1, so g = sel(L,y)+Q)
        if (lane < CH) {
            int   yv = ibp[32 + lane];
            float4 Q = qlb[lane];
            float4 L = qlb[CH + lane];
            float hs0 = (yv == 0) ? L.x : L.y;
            float hs1 = (yv == 0) ? L.z : L.w;
            s_g[db][lane] = make_float4(hs0 + Q.x, hs1 + Q.y, hs0 + Q.z, hs1 + Q.w);
        }

        // ---- batched W pre-pass (alpha-free, independent sums) ----
        float Wv[CH - 1];
#pragma unroll
        for (int u = 0; u < CH - 1; ++u)
            Wv[u] = wave_sum(c0r[u + 1] * c0r[u] + c1r[u + 1] * c1r[u]);

        // ---- prime a2 for step 0 from fresh alpha ----
        float a20 = wave_sum(c0r[0] * al00 + c1r[0] * al10);
        float a21 = wave_sum(c0r[0] * al01 + c1r[0] * al11);

        float keep0 = 0.f, keep1 = 0.f;

        // ---- serial pass ----
#pragma unroll
        for (int u = 0; u < CH; ++u) {
            float4 g4 = s_g[db][u];
            keep0 = (lane == u) ? a20 : keep0;
            keep1 = (lane == u) ? a21 : keep1;
            if (u < CH - 1) {
                // U sums (use pre-update alpha; independent of a3)
                float x0 = c0r[u + 1] * c0r[u], x1 = c1r[u + 1] * c1r[u];
                float tu0 = c0r[u + 1] - x0,   tu1 = c1r[u + 1] - x1;
                float U0 = wave_sum(tu0 * al00 + tu1 * al10);
                float U1 = wave_sum(tu0 * al01 + tu1 * al11);
                // critical chain
                float a30 = lseb(g4.x + a20, g4.y + a21);
                float a31 = lseb(g4.z + a20, g4.w + a21);
                // alpha update
                al00 += c0r[u] * (a30 - al00);
                al01 += c0r[u] * (a31 - al01);
                al10 += c1r[u] * (a30 - al10);
                al11 += c1r[u] * (a31 - al11);
                // next a2 = U + W*a3
                a20 = U0 + Wv[u] * a30;
                a21 = U1 + Wv[u] * a31;
            } else {
                float a30 = lseb(g4.x + a20, g4.y + a21);
                float a31 = lseb(g4.z + a20, g4.w + a21);
                al00 += c0r[u] * (a30 - al00);
                al01 += c0r[u] * (a31 - al01);
                al10 += c1r[u] * (a30 - al10);
                al11 += c1r[u] * (a31 - al11);
            }
        }

        // ---- py epilogue: lanes 0..15, one step each; output *= ln2 ----
        if (lane < CH) {
            float4 L = qlb[CH + lane];
            float py0 = lseb(L.x + keep0, L.z + keep1);
            float py1 = lseb(L.y + keep0, L.w + keep1);
            float nrm = lseb(py0, py1);
            int t = n * CH + lane;
            if (t < T_)
                *reinterpret_cast<float2*>(outp + (size_t)t * 2) =
                    make_float2((py0 - nrm) * LN2_, (py1 - nrm) * LN2_);
        }
    }
#undef STAGEIDX
#undef GATHER
}

extern "C" void kernel_launch(void* const* d_in, const int* in_sizes, int n_in,
                              void* d_out, int out_size, void* d_ws, size_t ws_size,
                              hipStream_t stream) {
    const int*   corr    = (const int*)d_in[0];
    const int*   kc      = (const int*)d_in[1];
    const int*   problem = (const int*)d_in[2];
    const float* A       = (const float*)d_in[3];
    const float* trans   = (const float*)d_in[4];
    const float* obs     = (const float*)d_in[5];
    const float* init    = (const float*)d_in[6];
    float* out = (float*)d_out;

    // workspace layout: Qtab (NP*4 f32) | LOtab (NP*4 f32)
    float* Qtab  = (float*)d_ws;
    float* LOtab = Qtab + (size_t)NP_ * 4;

    bkt_pre<<<NP_, 64, 0, stream>>>(A, trans, obs, Qtab, LOtab);
    bkt_main<<<B_, 64, 0, stream>>>(corr, kc, problem, A, init, Qtab, LOtab, out);
}

// Round 12
// 241.248 us; speedup vs baseline: 1.5419x; 1.0899x over previous
//
#include <hip/hip_runtime.h>
#include <math.h>

#define B_  1024
#define T_  500
#define K_  100
#define NP_ 10000
#define CH  16          // steps per chunk
#define NCH 32          // 32*16 = 512 >= T_

#define LOG2E_ 1.4426950408889634f
#define LN2_   0.6931471805599453f

// natural-log lse2 (used in precompute only)
__device__ __forceinline__ float lse2(float a, float b) {
    float m = fmaxf(a, b);
    return m + __logf(__expf(a - m) + __expf(b - m));
}

// base-2 lse2: max + log2(1 + 2^(min-max)); 2 trans ops, no conversion muls
__device__ __forceinline__ float lseb(float a, float b) {
    float mx = fmaxf(a, b);
    float d  = fminf(a, b) - mx;          // <= 0
    return mx + log2f(1.f + exp2f(d));
}

template<int CTRL, int RM>
__device__ __forceinline__ float dpp_add(float v) {
    int x = __builtin_amdgcn_update_dpp(0, __float_as_int(v), CTRL, RM, 0xf, true);
    return v + __int_as_float(x);
}

// Full-wave64 sum (6 stages), result uniform via readlane(63). (precompute only)
__device__ __forceinline__ float wave_sum(float v) {
    v = dpp_add<0x111, 0xf>(v);
    v = dpp_add<0x112, 0xf>(v);
    v = dpp_add<0x114, 0xf>(v);
    v = dpp_add<0x118, 0xf>(v);
    v = dpp_add<0x142, 0xa>(v);   // row_bcast:15 -> rows 1,3
    v = dpp_add<0x143, 0xc>(v);   // row_bcast:31 -> rows 2,3
    return __int_as_float(__builtin_amdgcn_readlane(__float_as_int(v), 63));
}

// 5-stage half-wave sums: returns (sum lanes 0..31, sum lanes 32..63)
__device__ __forceinline__ float2 half_sum2(float v) {
    v = dpp_add<0x111, 0xf>(v);
    v = dpp_add<0x112, 0xf>(v);
    v = dpp_add<0x114, 0xf>(v);
    v = dpp_add<0x118, 0xf>(v);
    v = dpp_add<0x142, 0xa>(v);   // row_bcast:15 -> rows 1,3
    float lo = __int_as_float(__builtin_amdgcn_readlane(__float_as_int(v), 31));
    float hi = __int_as_float(__builtin_amdgcn_readlane(__float_as_int(v), 63));
    return make_float2(lo, hi);
}

// 5-stage, lower-half result only (halves hold identical data)
__device__ __forceinline__ float half_sum_lo(float v) {
    v = dpp_add<0x111, 0xf>(v);
    v = dpp_add<0x112, 0xf>(v);
    v = dpp_add<0x114, 0xf>(v);
    v = dpp_add<0x118, 0xf>(v);
    v = dpp_add<0x142, 0xa>(v);
    return __int_as_float(__builtin_amdgcn_readlane(__float_as_int(v), 31));
}

// async global->LDS DMA: per-lane global src, linear LDS dest (base + lane*size)
#define GLOAD16(gp, lp) __builtin_amdgcn_global_load_lds( \
    (const __attribute__((address_space(1))) unsigned int*)(gp), \
    (__attribute__((address_space(3))) unsigned int*)(lp), 16, 0, 0)
#define GLOAD4(gp, lp) __builtin_amdgcn_global_load_lds( \
    (const __attribute__((address_space(1))) unsigned int*)(gp), \
    (__attribute__((address_space(3))) unsigned int*)(lp), 4, 0, 0)
#define WAITV0 asm volatile("s_waitcnt vmcnt(0)" ::: "memory")

// ---------------- precompute ----------
// Qtab[p] = (sum_k A[p,k] * log_softmax(trans,axis=1)[k]) * LOG2E
// LOtab[p] = log_softmax(obs[p], over o) * LOG2E   (sum_k A == 1, no Stab)
__global__ __launch_bounds__(64, 4) void bkt_pre(
    const float* __restrict__ A, const float* __restrict__ trans,
    const float* __restrict__ obs, float* __restrict__ Qtab,
    float* __restrict__ LOtab)
{
    const int p = blockIdx.x;
    const int lane = threadIdx.x;
    const int k0 = lane, k1 = lane + 64;
    const bool has1 = (k1 < K_);
    const int k1c = has1 ? k1 : k0;
    const float m1 = has1 ? 1.f : 0.f;

    float4 t0 = *reinterpret_cast<const float4*>(trans + k0 * 4);
    float l00 = lse2(t0.x, t0.z), l01 = lse2(t0.y, t0.w);
    float lt000 = t0.x - l00, lt001 = t0.y - l01;
    float lt010 = t0.z - l00, lt011 = t0.w - l01;
    float4 t1 = *reinterpret_cast<const float4*>(trans + k1c * 4);
    float l10 = lse2(t1.x, t1.z), l11 = lse2(t1.y, t1.w);
    float lt100 = t1.x - l10, lt101 = t1.y - l11;
    float lt110 = t1.z - l10, lt111 = t1.w - l11;

    const float* ar = A + (size_t)p * K_;
    float c0 = ar[k0];
    float c1 = ar[k1c] * m1;

    float q00 = wave_sum(c0 * lt000 + c1 * lt100);
    float q01 = wave_sum(c0 * lt001 + c1 * lt101);
    float q10 = wave_sum(c0 * lt010 + c1 * lt110);
    float q11 = wave_sum(c0 * lt011 + c1 * lt111);

    float4 ob = *reinterpret_cast<const float4*>(obs + (size_t)p * 4);
    float l0 = lse2(ob.x, ob.y), l1 = lse2(ob.z, ob.w);

    if (lane == 0) {
        reinterpret_cast<float4*>(Qtab)[p] =
            make_float4(q00 * LOG2E_, q01 * LOG2E_, q10 * LOG2E_, q11 * LOG2E_);
        reinterpret_cast<float4*>(LOtab)[p] =
            make_float4((ob.x - l0) * LOG2E_, (ob.y - l0) * LOG2E_,
                        (ob.z - l1) * LOG2E_, (ob.w - l1) * LOG2E_);
    }
}

// ---------------- main scan: state-split lanes, half-wave butterflies -------
// Lanes 0..31 hold state-0 alpha for KCs {l5, l5+32, l5+64, l5+96(m3)};
// lanes 32..63 hold state-1 for the same KCs. One 5-stage butterfly yields
// (a20, a21) via readlane(31), readlane(63).
__global__ __launch_bounds__(64, 1) void bkt_main(
    const int* __restrict__ corr, const int* __restrict__ kc,
    const int* __restrict__ problem, const float* __restrict__ A,
    const float* __restrict__ init, const float* __restrict__ Qtab,
    const float* __restrict__ LOtab, float* __restrict__ out)
{
    const int b = blockIdx.x;
    const int lane = threadIdx.x;
    const int l5 = lane & 31;
    const bool hi = lane >= 32;
    const float m3 = (l5 < 4) ? 1.f : 0.f;
    const int k3 = (l5 < 4) ? l5 + 96 : l5;   // clamped 4th KC

    // LDS staging (~14.6 KB)
    __shared__ float  s_c[2][CH * K_];      // A-rows per step    12800 B
    __shared__ float4 s_ql[2][2 * CH];      // Q[0..15] L[16..31]  1024 B
    __shared__ int    s_idx[3][3 * CH];     // kc|pr|y              576 B
    __shared__ float4 s_g[2][CH];           // per-step g           512 B

    const int* kcb = kc + (size_t)b * T_;
    const int* prb = problem + (size_t)b * T_;
    const int* cob = corr + (size_t)b * T_;
    float* outp = out + (size_t)b * T_ * 2;

    // alpha init: per-lane 4 KCs, state = hi; log2 domain
    float2 alA, alB;
    {
        float2 x0 = *reinterpret_cast<const float2*>(init + l5 * 2);
        float2 x1 = *reinterpret_cast<const float2*>(init + (l5 + 32) * 2);
        float2 x2 = *reinterpret_cast<const float2*>(init + (l5 + 64) * 2);
        float2 x3 = *reinterpret_cast<const float2*>(init + k3 * 2);
        float l0 = lse2(x0.x, x0.y), l1 = lse2(x1.x, x1.y);
        float l2 = lse2(x2.x, x2.y), l3 = lse2(x3.x, x3.y);
        alA.x = ((hi ? x0.y : x0.x) - l0) * LOG2E_;
        alA.y = ((hi ? x1.y : x1.x) - l1) * LOG2E_;
        alB.x = ((hi ? x2.y : x2.x) - l2) * LOG2E_;
        alB.y = ((hi ? x3.y : x3.x) - l3) * LOG2E_ * m3;
    }

    // idx stage: lanes 0..15 kc, 16..31 pr, 32..47 y (clamped t)
#define STAGEIDX(cn, ib) {                                                \
        int tt_ = (cn) * CH + (lane & 15);                                \
        tt_ = tt_ < T_ ? tt_ : T_ - 1;                                    \
        const int* src_ = (lane < 16) ? (kcb + tt_)                       \
                        : (lane < 32) ? (prb + tt_) : (cob + tt_);        \
        if (lane < 48) GLOAD4(src_, &s_idx[ib][0]);                       \
    }

#define GATHER(ib, db) {                                                  \
        int id_ = s_idx[ib][lane & 31];                                   \
        const float* qls_ = (lane < 16) ? (Qtab + (size_t)id_ * 4)        \
                                        : (LOtab + (size_t)id_ * 4);      \
        if (lane < 32) GLOAD16(qls_, &s_ql[db][0]);                       \
        _Pragma("unroll")                                                 \
        for (int j_ = 0; j_ < 7; ++j_) {                                  \
            int f_ = j_ * 64 + lane;                                      \
            unsigned tf_ = ((unsigned)f_ * 5243u) >> 17;    /* f/25 */    \
            int q_ = f_ - (int)tf_ * 25;                                  \
            int kcv_ = s_idx[ib][tf_];                                    \
            if (f_ < CH * 25)                                             \
                GLOAD16(A + (size_t)kcv_ * K_ + q_ * 4, &s_c[db][j_ * 256]); \
        }                                                                 \
    }

    // ---- prologue ----
    STAGEIDX(0, 0);
    STAGEIDX(1, 1);
    WAITV0;
    GATHER(0, 0);

#pragma unroll 1
    for (int n = 0; n < NCH; ++n) {
        WAITV0;                               // chunk-n data + idx n+1 landed
        STAGEIDX(n + 2, (n + 2) % 3);
        GATHER((n + 1) % 3, (n + 1) & 1);

        const float*  cbuf = s_c[n & 1];
        const float4* qlb  = s_ql[n & 1];
        const int*    ibp  = s_idx[n % 3];
        const int db = n & 1;

        // ---- c rows into registers (4 KCs per lane; both halves identical) --
        float2 crA[CH], crB[CH];
#pragma unroll
        for (int u = 0; u < CH; ++u) {
            crA[u] = make_float2(cbuf[u * K_ + l5], cbuf[u * K_ + l5 + 32]);
            crB[u] = make_float2(cbuf[u * K_ + l5 + 64], cbuf[u * K_ + k3] * m3);
        }

        // ---- g pre-pass: lanes 0..15, step = lane (S==1: g = sel(L,y)+Q) ----
        if (lane < CH) {
            int   yv = ibp[32 + lane];
            float4 Q = qlb[lane];
            float4 L = qlb[CH + lane];
            float hs0 = (yv == 0) ? L.x : L.y;
            float hs1 = (yv == 0) ? L.z : L.w;
            s_g[db][lane] = make_float4(hs0 + Q.x, hs1 + Q.y, hs0 + Q.z, hs1 + Q.w);
        }

        // ---- batched W pre-pass (alpha-free) ----
        float Wv[CH - 1];
#pragma unroll
        for (int u = 0; u < CH - 1; ++u) {
            float w = crA[u + 1].x * crA[u].x + crA[u + 1].y * crA[u].y
                    + crB[u + 1].x * crB[u].x + crB[u + 1].y * crB[u].y;
            Wv[u] = half_sum_lo(w);
        }

        // ---- prime a2 for step 0 from fresh alpha ----
        float2 a2p = half_sum2(crA[0].x * alA.x + crA[0].y * alA.y
                             + crB[0].x * alB.x + crB[0].y * alB.y);
        float a20 = a2p.x, a21 = a2p.y;

        float keep0 = 0.f, keep1 = 0.f;
        float4 gc = s_g[db][0];

        // ---- serial pass ----
#pragma unroll
        for (int u = 0; u < CH; ++u) {
            float4 gn = (u < CH - 1) ? s_g[db][u + 1] : gc;   // prefetch next g
            keep0 = (lane == u) ? a20 : keep0;
            keep1 = (lane == u) ? a21 : keep1;
            float a30 = lseb(gc.x + a20, gc.y + a21);
            float a31 = lseb(gc.z + a20, gc.w + a21);
            if (u < CH - 1) {
                // U sums from pre-update alpha (independent of a3)
                float2 xA = make_float2(crA[u + 1].x * crA[u].x,
                                        crA[u + 1].y * crA[u].y);
                float2 xB = make_float2(crB[u + 1].x * crB[u].x,
                                        crB[u + 1].y * crB[u].y);
                float2 tA = make_float2(crA[u + 1].x - xA.x, crA[u + 1].y - xA.y);
                float2 tB = make_float2(crB[u + 1].x - xB.x, crB[u + 1].y - xB.y);
                float2 U = half_sum2(tA.x * alA.x + tA.y * alA.y
                                   + tB.x * alB.x + tB.y * alB.y);
                // alpha update (state = hi)
                float a3s = hi ? a31 : a30;
                alA.x += crA[u].x * (a3s - alA.x);
                alA.y += crA[u].y * (a3s - alA.y);
                alB.x += crB[u].x * (a3s - alB.x);
                alB.y += crB[u].y * (a3s - alB.y);
                // next a2 = U + W*a3
                a20 = U.x + Wv[u] * a30;
                a21 = U.y + Wv[u] * a31;
            } else {
                float a3s = hi ? a31 : a30;
                alA.x += crA[u].x * (a3s - alA.x);
                alA.y += crA[u].y * (a3s - alA.y);
                alB.x += crB[u].x * (a3s - alB.x);
                alB.y += crB[u].y * (a3s - alB.y);
            }
            gc = gn;
        }

        // ---- py epilogue: lanes 0..15, one step each; output *= ln2 ----
        if (lane < CH) {
            float4 L = qlb[CH + lane];
            float py0 = lseb(L.x + keep0, L.z + keep1);
            float py1 = lseb(L.y + keep0, L.w + keep1);
            float nrm = lseb(py0, py1);
            int t = n * CH + lane;
            if (t < T_)
                *reinterpret_cast<float2*>(outp + (size_t)t * 2) =
                    make_float2((py0 - nrm) * LN2_, (py1 - nrm) * LN2_);
        }
    }
#undef STAGEIDX
#undef GATHER
}

extern "C" void kernel_launch(void* const* d_in, const int* in_sizes, int n_in,
                              void* d_out, int out_size, void* d_ws, size_t ws_size,
                              hipStream_t stream) {
    const int*   corr    = (const int*)d_in[0];
    const int*   kc      = (const int*)d_in[1];
    const int*   problem = (const int*)d_in[2];
    const float* A       = (const float*)d_in[3];
    const float* trans   = (const float*)d_in[4];
    const float* obs     = (const float*)d_in[5];
    const float* init    = (const float*)d_in[6];
    float* out = (float*)d_out;

    // workspace layout: Qtab (NP*4 f32) | LOtab (NP*4 f32)
    float* Qtab  = (float*)d_ws;
    float* LOtab = Qtab + (size_t)NP_ * 4;

    bkt_pre<<<NP_, 64, 0, stream>>>(A, trans, obs, Qtab, LOtab);
    bkt_main<<<B_, 64, 0, stream>>>(corr, kc, problem, A, init, Qtab, LOtab, out);
}